// Round 5
// baseline (19.794 us; speedup 1.0000x reference)
//
#include <hip/hip_runtime.h>
#include <math.h>

#define NQ 10
#define NLAYERS 4
#define IDIM 768
#define BLK 256   // one block = TWO batch elements; 4 amps/lane/element

typedef float f32x2 __attribute__((ext_vector_type(2)));

// ---------------------------------------------------------------------------
// Compile-time circuit plan (identical to rounds 3-4, absmax = 0 verified).
// Index bit b <-> wire w = 9-b. CNOT ring = GF(2)-linear map P on indices.
// Gates run in bit-permuted storage bases so no gate crosses wave bits; one
// LDS transpose switches basis. RZ layers collapse to one diagonal pass.
// ---------------------------------------------------------------------------
constexpr int cpop(unsigned v){int c=0;for(;v;v>>=1)c+=(int)(v&1u);return c;}

struct Mats { unsigned Prow[5][NQ]; unsigned Qrow[4][NQ]; };

constexpr Mats make_mats(){
    Mats M{};
    unsigned P[NQ]={},Q[NQ]={};
    for(int b=0;b<NQ;++b){P[b]=1u<<b;Q[b]=1u<<b;}
    for(int w=0;w<NQ;++w){const int c=9-w,t=9-((w+1)%NQ);P[t]^=P[c];}
    for(int w=NQ-1;w>=0;--w){const int c=9-w,t=9-((w+1)%NQ);Q[t]^=Q[c];}
    for(int b=0;b<NQ;++b){M.Prow[0][b]=1u<<b;M.Qrow[0][b]=1u<<b;}
    for(int l=1;l<=4;++l)for(int i=0;i<NQ;++i){
        unsigned r=0;for(int j=0;j<NQ;++j)if((P[i]>>j)&1u)r^=M.Prow[l-1][j];
        M.Prow[l][i]=r;}
    for(int l=1;l<=3;++l)for(int i=0;i<NQ;++i){
        unsigned r=0;for(int j=0;j<NQ;++j)if((Q[i]>>j)&1u)r^=M.Qrow[l-1][j];
        M.Qrow[l][i]=r;}
    return M;
}
constexpr Mats MT = make_mats();

constexpr unsigned qcol(int l,int b){
    unsigned m=0;for(int j=0;j<NQ;++j)m|=((MT.Qrow[l][j]>>b)&1u)<<j;return m;
}

constexpr int BASIS[5][NQ]={
 {0,1,2,3,4,5,6,7,8,9},   // B0: wave = orig {8,9}
 {0,1,2,3,8,5,9,7,4,6},   // B1: wave = orig {4,6}
 {0,1,2,3,8,4,9,6,5,7},   // B2: wave = orig {5,7}
 {0,1,5,7,8,4,9,6,2,3},   // B3a: wave = orig {2,3}
 {0,1,5,7,2,4,3,6,8,9}};  // B3b: wave = orig {8,9}

constexpr unsigned xfm(unsigned g,int bi){
    unsigned m=0;for(int p=0;p<NQ;++p)m|=((g>>BASIS[bi][p])&1u)<<p;return m;
}

constexpr int STAGE[3][NQ]={
 {1,1,0,0,0,0,0,0,0,1},
 {1,2,1,2,1,2,1,1,1,1},
 {3,3,3,4,4,2,2,2,3,2}};

constexpr int TPAIR[4][2]={{0,1},{1,2},{2,3},{3,4}};
constexpr int tsrc(int k,int p){
    const int a=TPAIR[k][0],b=TPAIR[k][1];
    const int orig=BASIS[a][p+2];
    int q=-1;for(int i=0;i<NQ;++i)if(BASIS[b][i]==orig)q=i;
    return q-2;
}

constexpr bool sched_ok(){
    for(int l=1;l<=3;++l)for(int w=0;w<NQ;++w){
        const unsigned g=qcol(l,9-w), r=MT.Prow[l][9-w];
        const int bi=STAGE[l-1][w];
        const unsigned m=xfm(g,bi), rr=xfm(r,bi);
        if(m==0) return false;
        if(m>>8) return false;
        if(!(cpop(m&rr)&1)) return false;
    }
    for(int bi=0;bi<5;++bi){
        if(BASIS[bi][0]!=0||BASIS[bi][1]!=1) return false;
        unsigned seen=0;for(int p=0;p<NQ;++p)seen|=1u<<BASIS[bi][p];
        if(seen!=0x3FFu) return false;
    }
    for(int k=0;k<4;++k)for(int p=0;p<8;++p){
        if(tsrc(k,p)<0||tsrc(k,p)>=8) return false;
    }
    return true;
}
static_assert(sched_ok(),"bad schedule");

struct RowPlan { unsigned short rt[NQ]; unsigned char rl[NQ]; };
constexpr RowPlan rplan(int l,int bi){
    RowPlan d{};
    for(int w=0;w<NQ;++w){
        const unsigned r=xfm(MT.Prow[l][9-w],bi);
        d.rt[w]=(unsigned short)(r>>2); d.rl[w]=(unsigned char)(r&3);
    }
    return d;
}
constexpr RowPlan DP1=rplan(1,1), DP2=rplan(2,2), ZP=rplan(4,4);

// ---------------------------------------------------------------------------
// packed f32 helpers (CDNA full-rate packed FP32)
__device__ __forceinline__ f32x2 pk_fma(f32x2 a, f32x2 b, f32x2 c){
    f32x2 d;
    asm("v_pk_fma_f32 %0, %1, %2, %3" : "=v"(d) : "v"(a), "v"(b), "v"(c));
    return d;
}
__device__ __forceinline__ f32x2 pk_mul(f32x2 a, f32x2 b){
    f32x2 d;
    asm("v_pk_mul_f32 %0, %1, %2" : "=v"(d) : "v"(a), "v"(b));
    return d;
}
__device__ __forceinline__ f32x2 b2v(float s){ f32x2 r; r[0]=s; r[1]=s; return r; }

template<int LM>
__device__ __forceinline__ float lxor(float v){
    if constexpr (LM==0) return v;
    else if constexpr (LM<32)
        return __int_as_float(__builtin_amdgcn_ds_swizzle(__float_as_int(v),(LM<<10)|0x1F));
    else
        return __shfl_xor(v,LM,64);
}
template<int LM>
__device__ __forceinline__ f32x2 lxor2(f32x2 v){
    f32x2 r; r[0]=lxor<LM>(v[0]); r[1]=lxor<LM>(v[1]); return r;
}
__device__ __forceinline__ float red64(float s){
    s += lxor<32>(s); s += lxor<16>(s); s += lxor<8>(s);
    s += lxor<4>(s);  s += lxor<2>(s);  s += lxor<1>(s);
    return s;
}

// RY gate at (layer L, wire W) applied to BOTH elements' states u, v.
// Control math (signs) shared; arithmetic packed (re,im).
template<int L,int W>
__device__ __forceinline__ void ry2(f32x2 (&u)[4], f32x2 (&v)[4],
                                    const float2* __restrict__ sG,int tid){
    constexpr unsigned m = xfm(qcol(L,9-W), STAGE[L-1][W]);
    constexpr unsigned r = xfm(MT.Prow[L][9-W], STAGE[L-1][W]);
    constexpr int ml=(int)(m&3u), lm=(int)((m>>2)&63u);
    constexpr int rt=(int)(r>>2), rl=(int)(r&3u);
    const float2 g = sG[(L-1)*NQ+W];
    const float cy=g.x, sy=g.y;
    const f32x2 cy2 = b2v(cy);
    const int pb=__popc(tid&rt)&1;
    const float syP = pb? sy : -sy;

    if constexpr (lm==0){
        #pragma unroll
        for(int j=0;j<4;++j){
            const int k=j^ml;
            if(j<k){
                const float sJ=((__popc(j&rl)&1)? -syP:syP);
                const f32x2 sJ2=b2v(sJ), nJ2=b2v(-sJ);
                const f32x2 aj=u[j], bk=u[k];
                u[j]=pk_fma(bk,sJ2,pk_mul(aj,cy2));
                u[k]=pk_fma(aj,nJ2,pk_mul(bk,cy2));
                const f32x2 cj=v[j], dk=v[k];
                v[j]=pk_fma(dk,sJ2,pk_mul(cj,cy2));
                v[k]=pk_fma(cj,nJ2,pk_mul(dk,cy2));
            }
        }
    } else {
        f32x2 ou[4],ov[4];
        #pragma unroll
        for(int q=0;q<4;++q){ou[q]=u[q];ov[q]=v[q];}
        #pragma unroll
        for(int j=0;j<4;++j){
            const f32x2 pu=lxor2<lm>(ou[j^ml]);
            const f32x2 pv=lxor2<lm>(ov[j^ml]);
            const float sE=((__popc(j&rl)&1)? -syP:syP);
            const f32x2 sE2=b2v(sE);
            u[j]=pk_fma(pu,sE2,pk_mul(ou[j],cy2));
            v[j]=pk_fma(pv,sE2,pk_mul(ov[j],cy2));
        }
    }
}

// basis-change transpose (both elements) through double-buffered LDS
template<int K>
__device__ __forceinline__ void transp2(f32x2 (&u)[4], f32x2 (&v)[4],
                                        float (*sT)[4][1024], int tid,int& pp){
    float (*B)[1024] = sT[pp];
    const int base = tid<<2;
    *reinterpret_cast<float4*>(&B[0][base]) = make_float4(u[0][0],u[1][0],u[2][0],u[3][0]);
    *reinterpret_cast<float4*>(&B[1][base]) = make_float4(u[0][1],u[1][1],u[2][1],u[3][1]);
    *reinterpret_cast<float4*>(&B[2][base]) = make_float4(v[0][0],v[1][0],v[2][0],v[3][0]);
    *reinterpret_cast<float4*>(&B[3][base]) = make_float4(v[0][1],v[1][1],v[2][1],v[3][1]);
    __syncthreads();
    int ot=0;
    #pragma unroll
    for(int p=0;p<8;++p) ot |= ((tid>>tsrc(K,p))&1)<<p;
    const int ob=ot<<2;
    const float4 r0=*reinterpret_cast<const float4*>(&B[0][ob]);
    const float4 i0=*reinterpret_cast<const float4*>(&B[1][ob]);
    const float4 r1=*reinterpret_cast<const float4*>(&B[2][ob]);
    const float4 i1=*reinterpret_cast<const float4*>(&B[3][ob]);
    u[0][0]=r0.x;u[1][0]=r0.y;u[2][0]=r0.z;u[3][0]=r0.w;
    u[0][1]=i0.x;u[1][1]=i0.y;u[2][1]=i0.z;u[3][1]=i0.w;
    v[0][0]=r1.x;v[1][0]=r1.y;v[2][0]=r1.z;v[3][0]=r1.w;
    v[0][1]=i1.x;v[1][1]=i1.y;v[2][1]=i1.z;v[3][1]=i1.w;
    pp^=1;
}

// one layer's RZs as a single diagonal pass; phases shared by both elements
__device__ __forceinline__ void diag2(f32x2 (&u)[4], f32x2 (&v)[4],
                                      const RowPlan& dp,
                                      const float* __restrict__ hz,int tid){
    float G[4]={0.f,0.f,0.f,0.f};
    #pragma unroll
    for(int w=0;w<NQ;++w){
        const int pb=__popc(tid&dp.rt[w])&1;
        G[dp.rl[w]] += pb? hz[w] : -hz[w];
    }
    const float ph[4]={G[0]+G[1]+G[2]+G[3], G[0]-G[1]+G[2]-G[3],
                       G[0]+G[1]-G[2]-G[3], G[0]-G[1]-G[2]+G[3]};
    #pragma unroll
    for(int j=0;j<4;++j){
        float s_,c_; __sincosf(ph[j],&s_,&c_);
        const float xu=u[j][0], yu=u[j][1];
        u[j][0]=fmaf(c_,xu,-s_*yu); u[j][1]=fmaf(c_,yu,s_*xu);
        const float xv=v[j][0], yv=v[j][1];
        v[j][0]=fmaf(c_,xv,-s_*yv); v[j][1]=fmaf(c_,yv,s_*xv);
    }
}

__global__ __launch_bounds__(BLK) void qhead_kernel(
    const float* __restrict__ x,    // [B, 768]
    const float* __restrict__ Wr,   // [10, 768]
    const float* __restrict__ br,   // [10]
    const float* __restrict__ wts,  // [4, 10, 2]
    const float* __restrict__ Wo,   // [1, 10]
    const float* __restrict__ bo,   // [1]
    float* __restrict__ out)        // [B]
{
    __shared__ __align__(16) float sT[2][4][1024];     // transpose bufs 32 KB
    __shared__ __align__(8)  float2 sG2[3*NQ];         // (cy,sy) layers 1..3
    __shared__ float sA[2][NQ],sCa[2][NQ],sSa[2][NQ];
    __shared__ float sHz0[NQ],sHz1[NQ],sHz2[NQ],sWo[NQ];
    __shared__ f32x2 sRed2[4];
    __shared__ float sBo;

    const int t   =threadIdx.x;
    const int lane=t&63;
    const int wv  =t>>6;
    const int bid =blockIdx.x;

    // ---- setup (parallel with GEMM loads); weights shared by both elements
    if(t<60){
        const int g=t>>1,l=g/NQ+1,w=g%NQ;
        const float h=0.5f*wts[(l*NQ+w)*2];
        reinterpret_cast<float*>(sG2)[t]=(t&1)? __sinf(h):__cosf(h);
    } else if(t<70)  sHz0[t-60]=0.5f*wts[(t-60)*2+1];
    else if(t<80)    sHz1[t-70]=0.5f*wts[((t-70)+NQ)*2+1];
    else if(t<90)    sHz2[t-80]=0.5f*wts[((t-80)+2*NQ)*2+1];
    else if(t<100)   sWo[t-90]=Wo[t-90];
    else if(t==100)  sBo=bo[0];

    // ---- embedding GEMM: wave wv -> element (wv>>1), qubits (wv&1)+2k ----
    const int e   = wv>>1;
    const int qb  = wv&1;
    const float4* xp=reinterpret_cast<const float4*>(x)
                     +(size_t)(2*bid+e)*(IDIM/4);
    const float4 xv0=xp[lane],xv1=xp[64+lane],xv2=xp[128+lane];
    #pragma unroll
    for(int k=0;k<5;++k){
        const int q=qb+2*k;
        const float4* wp=reinterpret_cast<const float4*>(Wr)+q*(IDIM/4);
        const float4 w0=wp[lane],w1=wp[64+lane],w2=wp[128+lane];
        float s=xv0.x*w0.x+xv0.y*w0.y+xv0.z*w0.z+xv0.w*w0.w
               +xv1.x*w1.x+xv1.y*w1.y+xv1.z*w1.z+xv1.w*w1.w
               +xv2.x*w2.x+xv2.y*w2.y+xv2.z*w2.z+xv2.w*w2.w;
        s=red64(s);
        if(lane==0){
            const float ex=__expf(2.f*(s+br[q]));               // fast tanh
            sA[e][q]=(1.f-__fdividef(2.f,ex+1.f))*1.57079632679489662f
                    +wts[q*2];                                   // + layer-0 RY
        }
    }
    __syncthreads();

    if(t<20)          sCa[t/NQ][t%NQ]        =__cosf(0.5f*sA[t/NQ][t%NQ]);
    else if(t<40)     sSa[(t-20)/NQ][(t-20)%NQ]=__sinf(0.5f*sA[(t-20)/NQ][(t-20)%NQ]);
    __syncthreads();

    // ---- closed-form init @B0; phase (RZ0) shared, amplitudes per element
    float acu=1.f,acv=1.f,ph=0.f;
    #pragma unroll
    for(int w=0;w<8;++w){                 // wires 0..7 <-> tid bits 7..0
        const int bit=(t>>(7-w))&1;
        acu*=bit? sSa[0][w]:sCa[0][w];
        acv*=bit? sSa[1][w]:sCa[1][w];
        ph +=bit? sHz0[w]:-sHz0[w];
    }
    f32x2 u[4],v[4];
    #pragma unroll
    for(int j=0;j<4;++j){                 // wires 8,9 <-> slot bits 1,0
        const float aU=acu*((j&2)?sSa[0][8]:sCa[0][8])*((j&1)?sSa[0][9]:sCa[0][9]);
        const float aV=acv*((j&2)?sSa[1][8]:sCa[1][8])*((j&1)?sSa[1][9]:sCa[1][9]);
        const float pp_=ph+((j&2)?sHz0[8]:-sHz0[8])+((j&1)?sHz0[9]:-sHz0[9]);
        float s_,c_; __sincosf(pp_,&s_,&c_);
        u[j][0]=aU*c_; u[j][1]=aU*s_;
        v[j][0]=aV*c_; v[j][1]=aV*s_;
    }

    // ---- layers 1..3 ----
    int pp=0;
    ry2<1,2>(u,v,sG2,t); ry2<1,3>(u,v,sG2,t); ry2<1,4>(u,v,sG2,t);
    ry2<1,5>(u,v,sG2,t); ry2<1,6>(u,v,sG2,t); ry2<1,7>(u,v,sG2,t);
    ry2<1,8>(u,v,sG2,t);
    transp2<0>(u,v,sT,t,pp);
    ry2<1,0>(u,v,sG2,t); ry2<1,1>(u,v,sG2,t); ry2<1,9>(u,v,sG2,t);
    diag2(u,v,DP1,sHz1,t);

    ry2<2,0>(u,v,sG2,t); ry2<2,2>(u,v,sG2,t); ry2<2,4>(u,v,sG2,t);
    ry2<2,6>(u,v,sG2,t); ry2<2,7>(u,v,sG2,t); ry2<2,8>(u,v,sG2,t);
    ry2<2,9>(u,v,sG2,t);
    transp2<1>(u,v,sT,t,pp);
    ry2<2,1>(u,v,sG2,t); ry2<2,3>(u,v,sG2,t); ry2<2,5>(u,v,sG2,t);
    diag2(u,v,DP2,sHz2,t);

    ry2<3,5>(u,v,sG2,t); ry2<3,6>(u,v,sG2,t); ry2<3,7>(u,v,sG2,t);
    ry2<3,9>(u,v,sG2,t);
    transp2<2>(u,v,sT,t,pp);
    ry2<3,0>(u,v,sG2,t); ry2<3,1>(u,v,sG2,t); ry2<3,2>(u,v,sG2,t);
    ry2<3,8>(u,v,sG2,t);
    transp2<3>(u,v,sT,t,pp);
    ry2<3,3>(u,v,sG2,t); ry2<3,4>(u,v,sG2,t);
    // (layer-3 RZ is a pure phase before |.|^2 readout: dropped)

    // ---- readout @B3b; g(s) shared by both elements ----
    float G[4]={0.f,0.f,0.f,0.f};
    #pragma unroll
    for(int w=0;w<NQ;++w){
        const int pb=__popc(t&ZP.rt[w])&1;
        G[ZP.rl[w]] += pb? -sWo[w]:sWo[w];
    }
    const float g[4]={G[0]+G[1]+G[2]+G[3], G[0]-G[1]+G[2]-G[3],
                      G[0]+G[1]-G[2]-G[3], G[0]-G[1]-G[2]+G[3]};
    f32x2 acc; acc[0]=0.f; acc[1]=0.f;
    #pragma unroll
    for(int j=0;j<4;++j){
        acc[0]=fmaf(fmaf(u[j][0],u[j][0],u[j][1]*u[j][1]),g[j],acc[0]);
        acc[1]=fmaf(fmaf(v[j][0],v[j][0],v[j][1]*v[j][1]),g[j],acc[1]);
    }
    acc += lxor2<32>(acc); acc += lxor2<16>(acc); acc += lxor2<8>(acc);
    acc += lxor2<4>(acc);  acc += lxor2<2>(acc);  acc += lxor2<1>(acc);
    if(lane==0) sRed2[wv]=acc;
    __syncthreads();
    if(t==0){
        const f32x2 tot=sRed2[0]+sRed2[1]+sRed2[2]+sRed2[3];
        out[2*bid+0]=__fdividef(1.f,1.f+__expf(-(tot[0]+sBo)));
        out[2*bid+1]=__fdividef(1.f,1.f+__expf(-(tot[1]+sBo)));
    }
}

extern "C" void kernel_launch(void* const* d_in, const int* in_sizes, int n_in,
                              void* d_out, int out_size, void* d_ws, size_t ws_size,
                              hipStream_t stream) {
    const float* x  =(const float*)d_in[0];
    const float* Wr =(const float*)d_in[1];
    const float* br =(const float*)d_in[2];
    const float* wts=(const float*)d_in[3];
    const float* Wo =(const float*)d_in[4];
    const float* bo =(const float*)d_in[5];
    float* out=(float*)d_out;
    const int B=in_sizes[0]/IDIM;  // 1024

    qhead_kernel<<<B/2,BLK,0,stream>>>(x,Wr,br,wts,Wo,bo,out);
}

// Round 6
// 18.098 us; speedup vs baseline: 1.0937x; 1.0937x over previous
//
#include <hip/hip_runtime.h>
#include <math.h>

#define NQ 10
#define NLAYERS 4
#define IDIM 768
#define BLK 256   // one block = one batch element; 4 amps per thread (packed re,im)

typedef float f32x2 __attribute__((ext_vector_type(2)));

// ---------------------------------------------------------------------------
// Compile-time circuit plan (machinery validated rounds 2-5, absmax = 0).
// Index bit b <-> wire w = 9-b. CNOT ring = GF(2)-linear map P on indices.
// Gates run in bit-permuted storage bases chosen so (a) no gate crosses wave
// bits and (b) as many gates as possible land on reg bits (slot pos 0,1) or
// DPP-able lane bits (slot pos 2,3 -> quad_perm xor 1/2/3). One LDS transpose
// switches basis (now a general 10-bit permutation incl. reg bits). RZ layers
// collapse to one diagonal phase pass per layer.
// ---------------------------------------------------------------------------
constexpr int cpop(unsigned v){int c=0;for(;v;v>>=1)c+=(int)(v&1u);return c;}

struct Mats { unsigned Prow[5][NQ]; unsigned Qrow[4][NQ]; };

constexpr Mats make_mats(){
    Mats M{};
    unsigned P[NQ]={},Q[NQ]={};
    for(int b=0;b<NQ;++b){P[b]=1u<<b;Q[b]=1u<<b;}
    for(int w=0;w<NQ;++w){const int c=9-w,t=9-((w+1)%NQ);P[t]^=P[c];}
    for(int w=NQ-1;w>=0;--w){const int c=9-w,t=9-((w+1)%NQ);Q[t]^=Q[c];}
    for(int b=0;b<NQ;++b){M.Prow[0][b]=1u<<b;M.Qrow[0][b]=1u<<b;}
    for(int l=1;l<=4;++l)for(int i=0;i<NQ;++i){
        unsigned r=0;for(int j=0;j<NQ;++j)if((P[i]>>j)&1u)r^=M.Prow[l-1][j];
        M.Prow[l][i]=r;}
    for(int l=1;l<=3;++l)for(int i=0;i<NQ;++i){
        unsigned r=0;for(int j=0;j<NQ;++j)if((Q[i]>>j)&1u)r^=M.Qrow[l-1][j];
        M.Qrow[l][i]=r;}
    return M;
}
constexpr Mats MT = make_mats();

constexpr unsigned qcol(int l,int b){
    unsigned m=0;for(int j=0;j<NQ;++j)m|=((MT.Qrow[l][j]>>b)&1u)<<j;return m;
}

// position p holds original bit BASIS[bi][p].
// pos 0,1 = reg bits; pos 2..7 = lane bits 0..5; pos 8,9 = wave bits.
// Wave sets (fixed by stage analysis): {8,9},{4,6},{5,7},{2,3},{8,9}.
// Positions 0..7 re-assigned per basis to maximize reg/DPP gates.
constexpr int BASIS[5][NQ]={
 {0,1,2,3,4,5,6,7,8,9},   // B0
 {8,9,7,0,1,3,5,2,4,6},   // B1
 {4,6,2,0,8,1,3,9,5,7},   // B2
 {6,7,8,9,5,4,0,1,2,3},   // B3a
 {3,4,5,6,2,0,1,7,8,9}};  // B3b

constexpr unsigned xfm(unsigned g,int bi){
    unsigned m=0;for(int p=0;p<NQ;++p)m|=((g>>BASIS[bi][p])&1u)<<p;return m;
}

constexpr int STAGE[3][NQ]={
 {1,1,0,0,0,0,0,0,0,1},
 {1,2,1,2,1,2,1,1,1,1},
 {3,3,3,4,4,2,2,2,3,2}};

constexpr int TPAIR[4][2]={{0,1},{1,2},{2,3},{3,4}};
// old-slot bit p is sourced from new-slot bit srcbit(k,p)
constexpr int srcbit(int k,int p){
    const int a=TPAIR[k][0],b2=TPAIR[k][1];
    const int orig=BASIS[a][p];
    int q=-1;for(int i=0;i<NQ;++i)if(BASIS[b2][i]==orig)q=i;
    return q;
}
// j-dependent part of the old-slot index (reg-bit sources)
constexpr unsigned osj_tab(int k,int j){
    unsigned os=0;
    for(int p=0;p<NQ;++p){const int s=srcbit(k,p); if(s>=0&&s<2) os|=((unsigned)(j>>s)&1u)<<p;}
    return os;
}

constexpr bool sched_ok(){
    for(int l=1;l<=3;++l)for(int w=0;w<NQ;++w){
        const unsigned g=qcol(l,9-w), r=MT.Prow[l][9-w];
        const int bi=STAGE[l-1][w];
        const unsigned m=xfm(g,bi), rr=xfm(r,bi);
        if(m==0) return false;
        if(m>>8) return false;               // must avoid wave bits
        if(!(cpop(m&rr)&1)) return false;    // pairing must flip the side
    }
    for(int bi=0;bi<5;++bi){
        unsigned seen=0;for(int p=0;p<NQ;++p)seen|=1u<<BASIS[bi][p];
        if(seen!=0x3FFu) return false;
    }
    for(int k=0;k<4;++k){
        unsigned seen=0;
        for(int p=0;p<NQ;++p){const int s=srcbit(k,p); if(s<0||s>9) return false; seen|=1u<<s;}
        if(seen!=0x3FFu) return false;
    }
    return true;
}
static_assert(sched_ok(),"bad schedule");

struct RowPlan { unsigned short rt[NQ]; unsigned char rl[NQ]; };
constexpr RowPlan rplan(int l,int bi){
    RowPlan d{};
    for(int w=0;w<NQ;++w){
        const unsigned r=xfm(MT.Prow[l][9-w],bi);
        d.rt[w]=(unsigned short)(r>>2); d.rl[w]=(unsigned char)(r&3);
    }
    return d;
}
constexpr RowPlan DP1=rplan(1,1), DP2=rplan(2,2), ZP=rplan(4,4);

// ---------------------------------------------------------------------------
// packed f32 helpers (CDNA full-rate packed FP32, proven in round 5)
__device__ __forceinline__ f32x2 pk_fma(f32x2 a, f32x2 b, f32x2 c){
    f32x2 d;
    asm("v_pk_fma_f32 %0, %1, %2, %3" : "=v"(d) : "v"(a), "v"(b), "v"(c));
    return d;
}
__device__ __forceinline__ f32x2 pk_mul(f32x2 a, f32x2 b){
    f32x2 d;
    asm("v_pk_mul_f32 %0, %1, %2" : "=v"(d) : "v"(a), "v"(b));
    return d;
}

// lane-xor dispatch: quad_perm DPP (VALU) for 1,2,3; ds_swizzle for 4..31;
// ds_bpermute (shfl) for >=32.  quad_perm ctrls: xor1=177, xor2=78, xor3=27.
template<int LM>
__device__ __forceinline__ float lx(float v){
    if constexpr (LM==0) return v;
    else if constexpr (LM==1)
        return __int_as_float(__builtin_amdgcn_mov_dpp(__float_as_int(v),177,0xF,0xF,false));
    else if constexpr (LM==2)
        return __int_as_float(__builtin_amdgcn_mov_dpp(__float_as_int(v),78,0xF,0xF,false));
    else if constexpr (LM==3)
        return __int_as_float(__builtin_amdgcn_mov_dpp(__float_as_int(v),27,0xF,0xF,false));
    else if constexpr (LM<32)
        return __int_as_float(__builtin_amdgcn_ds_swizzle(__float_as_int(v),(LM<<10)|0x1F));
    else
        return __shfl_xor(v,LM,64);
}
__device__ __forceinline__ float red64(float s){
    s+=lx<32>(s); s+=lx<16>(s); s+=lx<8>(s); s+=lx<4>(s); s+=lx<2>(s); s+=lx<1>(s);
    return s;
}

// RY gate at (layer L, wire W) in its scheduled basis. Slot s=(tid<<2)|j,
// state packed (re,im). new(s) = cy*old(s) + (side(s)? +sy:-sy)*old(s^m),
// side = parity(row & s).
template<int L,int W>
__device__ __forceinline__ void ryp(f32x2 (&u)[4], const float2* __restrict__ sG, int tid){
    constexpr unsigned m = xfm(qcol(L,9-W), STAGE[L-1][W]);
    constexpr unsigned r = xfm(MT.Prow[L][9-W], STAGE[L-1][W]);
    constexpr int ml=(int)(m&3u), lm=(int)((m>>2)&63u);
    constexpr int rt=(int)(r>>2), rl=(int)(r&3u);
    const float2 g = sG[(L-1)*NQ+W];
    const int pb = __popc(tid&rt)&1;
    const float syP = pb ? g.y : -g.y;
    f32x2 cy2; cy2[0]=g.x; cy2[1]=g.x;
    f32x2 sp;  sp[0]=syP;  sp[1]=syP;
    f32x2 sn;  sn[0]=-syP; sn[1]=-syP;
    if constexpr (lm==0){
        #pragma unroll
        for(int j=0;j<4;++j){
            const int k=j^ml;
            if(j<k){
                // syE(k) = -syE(j): checker guarantees parity(ml&rl)=1
                const bool pj=(__popc(j&rl)&1)!=0;
                const f32x2 sj = pj? sn:sp;
                const f32x2 sk = pj? sp:sn;
                const f32x2 a=u[j], b=u[k];
                u[j]=pk_fma(b,sj,pk_mul(a,cy2));
                u[k]=pk_fma(a,sk,pk_mul(b,cy2));
            }
        }
    } else {
        f32x2 o[4]={u[0],u[1],u[2],u[3]};
        #pragma unroll
        for(int j=0;j<4;++j){
            f32x2 p;
            p[0]=lx<lm>(o[j^ml][0]);
            p[1]=lx<lm>(o[j^ml][1]);
            const f32x2 s_=((__popc(j&rl)&1)!=0)? sn:sp;
            u[j]=pk_fma(p,s_,pk_mul(o[j],cy2));
        }
    }
}

// basis-change transpose: general 10-bit slot permutation through LDS
// (double-buffered, one barrier). Write 2x b128 linear; gather 4x b64.
template<int K>
__device__ __forceinline__ void transp(f32x2 (&u)[4], f32x2* __restrict__ B, int tid){
    float4* dst = reinterpret_cast<float4*>(&B[tid<<2]);
    float4 d0; d0.x=u[0][0]; d0.y=u[0][1]; d0.z=u[1][0]; d0.w=u[1][1];
    float4 d1; d1.x=u[2][0]; d1.y=u[2][1]; d1.z=u[3][0]; d1.w=u[3][1];
    dst[0]=d0; dst[1]=d1;
    __syncthreads();
    int ot=0;
    #pragma unroll
    for(int p=0;p<NQ;++p){
        const int s=srcbit(K,p);
        if(s>=2) ot |= ((tid>>(s-2))&1)<<p;
    }
    const f32x2 r0=B[ot|osj_tab(K,0)];
    const f32x2 r1=B[ot|osj_tab(K,1)];
    const f32x2 r2=B[ot|osj_tab(K,2)];
    const f32x2 r3=B[ot|osj_tab(K,3)];
    u[0]=r0; u[1]=r1; u[2]=r2; u[3]=r3;
}

// one layer's RZs as a single diagonal pass (4-group Walsh butterfly)
__device__ __forceinline__ void diagp(f32x2 (&u)[4], const RowPlan& dp,
                                      const float* __restrict__ hz, int tid){
    float G[4]={0.f,0.f,0.f,0.f};
    #pragma unroll
    for(int w=0;w<NQ;++w){
        const int pb=__popc(tid&dp.rt[w])&1;
        G[dp.rl[w]] += pb? hz[w] : -hz[w];
    }
    const float ph[4]={G[0]+G[1]+G[2]+G[3], G[0]-G[1]+G[2]-G[3],
                       G[0]+G[1]-G[2]-G[3], G[0]-G[1]-G[2]+G[3]};
    #pragma unroll
    for(int j=0;j<4;++j){
        float s_,c_; __sincosf(ph[j],&s_,&c_);
        const float re=u[j][0], im=u[j][1];
        u[j][0]=fmaf(c_,re,-s_*im);
        u[j][1]=fmaf(c_,im, s_*re);
    }
}

__global__ __launch_bounds__(BLK) void qhead_kernel(
    const float* __restrict__ x,    // [B, 768]
    const float* __restrict__ Wr,   // [10, 768]
    const float* __restrict__ br,   // [10]
    const float* __restrict__ wts,  // [4, 10, 2]
    const float* __restrict__ Wo,   // [1, 10]
    const float* __restrict__ bo,   // [1]
    float* __restrict__ out)        // [B]
{
    __shared__ __align__(16) f32x2 sT[2][1024];    // transpose dbuf  16 KB
    __shared__ __align__(8)  float2 sG2[3*NQ];     // (cy,sy) layers 1..3
    __shared__ float sA[NQ],sCa[NQ],sSa[NQ];
    __shared__ float sHz0[NQ],sHz1[NQ],sHz2[NQ],sWo[NQ];
    __shared__ float sRed[4];
    __shared__ float sBo;

    const int t   =threadIdx.x;
    const int lane=t&63;
    const int wv  =t>>6;
    const int b   =blockIdx.x;

    // ---- setup (parallel with GEMM loads) ----
    if(t<60){
        const int g=t>>1,l=g/NQ+1,w=g%NQ;
        const float h=0.5f*wts[(l*NQ+w)*2];
        reinterpret_cast<float*>(sG2)[t]=(t&1)? __sinf(h):__cosf(h);
    } else if(t<70)  sHz0[t-60]=0.5f*wts[(t-60)*2+1];
    else if(t<80)    sHz1[t-70]=0.5f*wts[((t-70)+NQ)*2+1];
    else if(t<90)    sHz2[t-80]=0.5f*wts[((t-80)+2*NQ)*2+1];
    else if(t<100)   sWo[t-90]=Wo[t-90];
    else if(t==100)  sBo=bo[0];

    // ---- embedding GEMM: wave wv handles q = wv, wv+4, wv+8 ----
    const float4* xp=reinterpret_cast<const float4*>(x)+(size_t)b*(IDIM/4);
    const float4 xv0=xp[lane],xv1=xp[64+lane],xv2=xp[128+lane];
    for(int q=wv;q<NQ;q+=4){
        const float4* wp=reinterpret_cast<const float4*>(Wr)+q*(IDIM/4);
        const float4 w0=wp[lane],w1=wp[64+lane],w2=wp[128+lane];
        float s=xv0.x*w0.x+xv0.y*w0.y+xv0.z*w0.z+xv0.w*w0.w
               +xv1.x*w1.x+xv1.y*w1.y+xv1.z*w1.z+xv1.w*w1.w
               +xv2.x*w2.x+xv2.y*w2.y+xv2.z*w2.z+xv2.w*w2.w;
        s=red64(s);
        if(lane==0){
            const float e=__expf(2.f*(s+br[q]));                 // fast tanh
            sA[q]=(1.f-__fdividef(2.f,e+1.f))*1.57079632679489662f
                 +wts[q*2];                                       // + layer-0 RY
        }
    }
    __syncthreads();

    if(t<NQ)           sCa[t]   =__cosf(0.5f*sA[t]);
    else if(t<2*NQ)    sSa[t-NQ]=__sinf(0.5f*sA[t-NQ]);
    __syncthreads();

    // ---- closed-form init @B0 (layer-0 RY merged + layer-0 RZ phases) ----
    float ac=1.f,ph=0.f;
    #pragma unroll
    for(int w=0;w<8;++w){                 // wires 0..7 <-> tid bits 7..0
        const int bit=(t>>(7-w))&1;
        ac*=bit? sSa[w]:sCa[w];
        ph+=bit? sHz0[w]:-sHz0[w];
    }
    f32x2 u[4];
    #pragma unroll
    for(int j=0;j<4;++j){                 // wires 8,9 <-> slot bits 1,0
        const float a =ac*((j&2)?sSa[8]:sCa[8])*((j&1)?sSa[9]:sCa[9]);
        const float pp_=ph+((j&2)?sHz0[8]:-sHz0[8])+((j&1)?sHz0[9]:-sHz0[9]);
        float s_,c_; __sincosf(pp_,&s_,&c_);
        u[j][0]=a*c_; u[j][1]=a*s_;
    }

    // ---- layers 1..3: RY gates + basis transposes + diagonal RZ passes ----
    int pp=0;
    ryp<1,2>(u,sG2,t); ryp<1,3>(u,sG2,t); ryp<1,4>(u,sG2,t);
    ryp<1,5>(u,sG2,t); ryp<1,6>(u,sG2,t); ryp<1,7>(u,sG2,t);
    ryp<1,8>(u,sG2,t);
    transp<0>(u,sT[pp],t); pp^=1;
    ryp<1,0>(u,sG2,t); ryp<1,1>(u,sG2,t); ryp<1,9>(u,sG2,t);
    diagp(u,DP1,sHz1,t);

    ryp<2,0>(u,sG2,t); ryp<2,2>(u,sG2,t); ryp<2,4>(u,sG2,t);
    ryp<2,6>(u,sG2,t); ryp<2,7>(u,sG2,t); ryp<2,8>(u,sG2,t);
    ryp<2,9>(u,sG2,t);
    transp<1>(u,sT[pp],t); pp^=1;
    ryp<2,1>(u,sG2,t); ryp<2,3>(u,sG2,t); ryp<2,5>(u,sG2,t);
    diagp(u,DP2,sHz2,t);

    ryp<3,5>(u,sG2,t); ryp<3,6>(u,sG2,t); ryp<3,7>(u,sG2,t);
    ryp<3,9>(u,sG2,t);
    transp<2>(u,sT[pp],t); pp^=1;
    ryp<3,0>(u,sG2,t); ryp<3,1>(u,sG2,t); ryp<3,2>(u,sG2,t);
    ryp<3,8>(u,sG2,t);
    transp<3>(u,sT[pp],t); pp^=1;
    ryp<3,3>(u,sG2,t); ryp<3,4>(u,sG2,t);
    // (layer-3 RZ is a pure phase before |.|^2 readout: dropped)

    // ---- readout @B3b: logit = sum_s p_s * g(s), Walsh butterfly for g ----
    float G[4]={0.f,0.f,0.f,0.f};
    #pragma unroll
    for(int w=0;w<NQ;++w){
        const int pb=__popc(t&ZP.rt[w])&1;
        G[ZP.rl[w]] += pb? -sWo[w]:sWo[w];
    }
    const float g0=G[0]+G[1]+G[2]+G[3], g1=G[0]-G[1]+G[2]-G[3];
    const float g2=G[0]+G[1]-G[2]-G[3], g3=G[0]-G[1]-G[2]+G[3];
    float acc=(u[0][0]*u[0][0]+u[0][1]*u[0][1])*g0;
    acc=fmaf(u[1][0]*u[1][0]+u[1][1]*u[1][1],g1,acc);
    acc=fmaf(u[2][0]*u[2][0]+u[2][1]*u[2][1],g2,acc);
    acc=fmaf(u[3][0]*u[3][0]+u[3][1]*u[3][1],g3,acc);
    acc=red64(acc);
    if(lane==0) sRed[wv]=acc;
    __syncthreads();
    if(t==0){
        const float logit=sRed[0]+sRed[1]+sRed[2]+sRed[3]+sBo;
        out[b]=__fdividef(1.f,1.f+__expf(-logit));
    }
}

extern "C" void kernel_launch(void* const* d_in, const int* in_sizes, int n_in,
                              void* d_out, int out_size, void* d_ws, size_t ws_size,
                              hipStream_t stream) {
    const float* x  =(const float*)d_in[0];
    const float* Wr =(const float*)d_in[1];
    const float* br =(const float*)d_in[2];
    const float* wts=(const float*)d_in[3];
    const float* Wo =(const float*)d_in[4];
    const float* bo =(const float*)d_in[5];
    float* out=(float*)d_out;
    const int B=in_sizes[0]/IDIM;  // 1024

    qhead_kernel<<<B,BLK,0,stream>>>(x,Wr,br,wts,Wo,bo,out);
}

// Round 7
// 17.760 us; speedup vs baseline: 1.1145x; 1.0190x over previous
//
#include <hip/hip_runtime.h>
#include <math.h>

#define NQ 10
#define NLAYERS 4
#define IDIM 768
#define BLK 256   // one block = one batch element; 4 amps per thread (packed re,im)

typedef float f32x2 __attribute__((ext_vector_type(2)));

// ---------------------------------------------------------------------------
// Compile-time circuit plan (machinery validated rounds 2-6, absmax = 0).
// Index bit b <-> wire w = 9-b. CNOT ring = GF(2)-linear map P on indices.
// Gates run in bit-permuted storage bases chosen so (a) no gate crosses wave
// bits and (b) as many gates as possible land on reg bits (slot pos 0,1) or
// DPP-able lane bits (pos 2,3 -> quad_perm xor 1/2/3). One LDS transpose
// switches basis. RZ layers collapse to one diagonal phase pass per layer.
// ---------------------------------------------------------------------------
constexpr int cpop(unsigned v){int c=0;for(;v;v>>=1)c+=(int)(v&1u);return c;}

struct Mats { unsigned Prow[5][NQ]; unsigned Qrow[4][NQ]; };

constexpr Mats make_mats(){
    Mats M{};
    unsigned P[NQ]={},Q[NQ]={};
    for(int b=0;b<NQ;++b){P[b]=1u<<b;Q[b]=1u<<b;}
    for(int w=0;w<NQ;++w){const int c=9-w,t=9-((w+1)%NQ);P[t]^=P[c];}
    for(int w=NQ-1;w>=0;--w){const int c=9-w,t=9-((w+1)%NQ);Q[t]^=Q[c];}
    for(int b=0;b<NQ;++b){M.Prow[0][b]=1u<<b;M.Qrow[0][b]=1u<<b;}
    for(int l=1;l<=4;++l)for(int i=0;i<NQ;++i){
        unsigned r=0;for(int j=0;j<NQ;++j)if((P[i]>>j)&1u)r^=M.Prow[l-1][j];
        M.Prow[l][i]=r;}
    for(int l=1;l<=3;++l)for(int i=0;i<NQ;++i){
        unsigned r=0;for(int j=0;j<NQ;++j)if((Q[i]>>j)&1u)r^=M.Qrow[l-1][j];
        M.Qrow[l][i]=r;}
    return M;
}
constexpr Mats MT = make_mats();

constexpr unsigned qcol(int l,int b){
    unsigned m=0;for(int j=0;j<NQ;++j)m|=((MT.Qrow[l][j]>>b)&1u)<<j;return m;
}

// position p holds original bit BASIS[bi][p].
// pos 0,1 = reg bits; pos 2..7 = lane bits 0..5; pos 8,9 = wave bits.
constexpr int BASIS[5][NQ]={
 {0,1,2,3,4,5,6,7,8,9},   // B0
 {8,9,7,0,1,3,5,2,4,6},   // B1
 {4,6,2,0,8,1,3,9,5,7},   // B2
 {6,7,8,9,5,4,0,1,2,3},   // B3a
 {3,4,5,6,2,0,1,7,8,9}};  // B3b

constexpr unsigned xfm(unsigned g,int bi){
    unsigned m=0;for(int p=0;p<NQ;++p)m|=((g>>BASIS[bi][p])&1u)<<p;return m;
}

constexpr int STAGE[3][NQ]={
 {1,1,0,0,0,0,0,0,0,1},
 {1,2,1,2,1,2,1,1,1,1},
 {3,3,3,4,4,2,2,2,3,2}};

constexpr int TPAIR[4][2]={{0,1},{1,2},{2,3},{3,4}};
constexpr int srcbit(int k,int p){
    const int a=TPAIR[k][0],b2=TPAIR[k][1];
    const int orig=BASIS[a][p];
    int q=-1;for(int i=0;i<NQ;++i)if(BASIS[b2][i]==orig)q=i;
    return q;
}
constexpr unsigned osj_tab(int k,int j){
    unsigned os=0;
    for(int p=0;p<NQ;++p){const int s=srcbit(k,p); if(s>=0&&s<2) os|=((unsigned)(j>>s)&1u)<<p;}
    return os;
}

constexpr bool sched_ok(){
    for(int l=1;l<=3;++l)for(int w=0;w<NQ;++w){
        const unsigned g=qcol(l,9-w), r=MT.Prow[l][9-w];
        const int bi=STAGE[l-1][w];
        const unsigned m=xfm(g,bi), rr=xfm(r,bi);
        if(m==0) return false;
        if(m>>8) return false;               // must avoid wave bits
        if(!(cpop(m&rr)&1)) return false;    // pairing must flip the side
    }
    for(int bi=0;bi<5;++bi){
        unsigned seen=0;for(int p=0;p<NQ;++p)seen|=1u<<BASIS[bi][p];
        if(seen!=0x3FFu) return false;
    }
    for(int k=0;k<4;++k){
        unsigned seen=0;
        for(int p=0;p<NQ;++p){const int s=srcbit(k,p); if(s<0||s>9) return false; seen|=1u<<s;}
        if(seen!=0x3FFu) return false;
    }
    return true;
}
static_assert(sched_ok(),"bad schedule");

struct RowPlan { unsigned short rt[NQ]; unsigned char rl[NQ]; };
constexpr RowPlan rplan(int l,int bi){
    RowPlan d{};
    for(int w=0;w<NQ;++w){
        const unsigned r=xfm(MT.Prow[l][9-w],bi);
        d.rt[w]=(unsigned short)(r>>2); d.rl[w]=(unsigned char)(r&3);
    }
    return d;
}
constexpr RowPlan DP1=rplan(1,1), DP2=rplan(2,2), ZP=rplan(4,4);

// ---------------------------------------------------------------------------
__device__ __forceinline__ f32x2 pk_fma(f32x2 a, f32x2 b, f32x2 c){
    f32x2 d;
    asm("v_pk_fma_f32 %0, %1, %2, %3" : "=v"(d) : "v"(a), "v"(b), "v"(c));
    return d;
}
__device__ __forceinline__ f32x2 pk_mul(f32x2 a, f32x2 b){
    f32x2 d;
    asm("v_pk_mul_f32 %0, %1, %2" : "=v"(d) : "v"(a), "v"(b));
    return d;
}

// lane-xor: quad_perm DPP (VALU) for 1,2,3; ds_swizzle 4..31; bpermute >=32
template<int LM>
__device__ __forceinline__ float lx(float v){
    if constexpr (LM==0) return v;
    else if constexpr (LM==1)
        return __int_as_float(__builtin_amdgcn_mov_dpp(__float_as_int(v),177,0xF,0xF,false));
    else if constexpr (LM==2)
        return __int_as_float(__builtin_amdgcn_mov_dpp(__float_as_int(v),78,0xF,0xF,false));
    else if constexpr (LM==3)
        return __int_as_float(__builtin_amdgcn_mov_dpp(__float_as_int(v),27,0xF,0xF,false));
    else if constexpr (LM<32)
        return __int_as_float(__builtin_amdgcn_ds_swizzle(__float_as_int(v),(LM<<10)|0x1F));
    else
        return __shfl_xor(v,LM,64);
}
__device__ __forceinline__ float red64(float s){
    s+=lx<32>(s); s+=lx<16>(s); s+=lx<8>(s); s+=lx<4>(s); s+=lx<2>(s); s+=lx<1>(s);
    return s;
}

// RY gate at (layer L, wire W). Slot s=(tid<<2)|j, tid=(wv<<6)|lane.
// side parity split: vector popc on lane bits, scalar popc on wave bits.
template<int L,int W>
__device__ __forceinline__ void ryp(f32x2 (&u)[4], const float2* __restrict__ sG,
                                    int lane, int wvs){
    constexpr unsigned m = xfm(qcol(L,9-W), STAGE[L-1][W]);
    constexpr unsigned r = xfm(MT.Prow[L][9-W], STAGE[L-1][W]);
    constexpr int ml=(int)(m&3u), lm=(int)((m>>2)&63u);
    constexpr int rt=(int)(r>>2), rl=(int)(r&3u);
    constexpr int rtl=rt&63, rtw=rt>>6;
    const float2 g = sG[(L-1)*NQ+W];
    const int pb = (__popc(lane&rtl) + __popc(wvs&rtw))&1;
    const float syP = pb ? g.y : -g.y;
    f32x2 cy2; cy2[0]=g.x; cy2[1]=g.x;
    f32x2 sp;  sp[0]=syP;  sp[1]=syP;
    f32x2 sn;  sn[0]=-syP; sn[1]=-syP;
    if constexpr (lm==0){
        #pragma unroll
        for(int j=0;j<4;++j){
            const int k=j^ml;
            if(j<k){
                const bool pj=(__popc(j&rl)&1)!=0;
                const f32x2 sj = pj? sn:sp;
                const f32x2 sk = pj? sp:sn;
                const f32x2 a=u[j], b=u[k];
                u[j]=pk_fma(b,sj,pk_mul(a,cy2));
                u[k]=pk_fma(a,sk,pk_mul(b,cy2));
            }
        }
    } else {
        f32x2 o[4]={u[0],u[1],u[2],u[3]};
        #pragma unroll
        for(int j=0;j<4;++j){
            f32x2 p;
            p[0]=lx<lm>(o[j^ml][0]);
            p[1]=lx<lm>(o[j^ml][1]);
            const f32x2 s_=((__popc(j&rl)&1)!=0)? sn:sp;
            u[j]=pk_fma(p,s_,pk_mul(o[j],cy2));
        }
    }
}

// basis-change transpose through double-buffered LDS (one barrier)
template<int K>
__device__ __forceinline__ void transp(f32x2 (&u)[4], f32x2* __restrict__ B, int tid){
    float4* dst = reinterpret_cast<float4*>(&B[tid<<2]);
    float4 d0; d0.x=u[0][0]; d0.y=u[0][1]; d0.z=u[1][0]; d0.w=u[1][1];
    float4 d1; d1.x=u[2][0]; d1.y=u[2][1]; d1.z=u[3][0]; d1.w=u[3][1];
    dst[0]=d0; dst[1]=d1;
    __syncthreads();
    int ot=0;
    #pragma unroll
    for(int p=0;p<NQ;++p){
        const int s=srcbit(K,p);
        if(s>=2) ot |= ((tid>>(s-2))&1)<<p;
    }
    const f32x2 r0=B[ot|osj_tab(K,0)];
    const f32x2 r1=B[ot|osj_tab(K,1)];
    const f32x2 r2=B[ot|osj_tab(K,2)];
    const f32x2 r3=B[ot|osj_tab(K,3)];
    u[0]=r0; u[1]=r1; u[2]=r2; u[3]=r3;
}

// one layer's RZs as one diagonal pass (4-group Walsh butterfly)
__device__ __forceinline__ void diagp(f32x2 (&u)[4], const RowPlan& dp,
                                      const float* __restrict__ hz,
                                      int lane, int wvs){
    float G[4]={0.f,0.f,0.f,0.f};
    #pragma unroll
    for(int w=0;w<NQ;++w){
        const int rtl=dp.rt[w]&63, rtw=dp.rt[w]>>6;
        const int pb=(__popc(lane&rtl) + __popc(wvs&rtw))&1;
        G[dp.rl[w]] += pb? hz[w] : -hz[w];
    }
    const float ph[4]={G[0]+G[1]+G[2]+G[3], G[0]-G[1]+G[2]-G[3],
                       G[0]+G[1]-G[2]-G[3], G[0]-G[1]-G[2]+G[3]};
    #pragma unroll
    for(int j=0;j<4;++j){
        float s_,c_; __sincosf(ph[j],&s_,&c_);
        const float re=u[j][0], im=u[j][1];
        u[j][0]=fmaf(c_,re,-s_*im);
        u[j][1]=fmaf(c_,im, s_*re);
    }
}

__global__ __launch_bounds__(BLK) void qhead_kernel(
    const float* __restrict__ x,    // [B, 768]
    const float* __restrict__ Wr,   // [10, 768]
    const float* __restrict__ br,   // [10]
    const float* __restrict__ wts,  // [4, 10, 2]
    const float* __restrict__ Wo,   // [1, 10]
    const float* __restrict__ bo,   // [1]
    float* __restrict__ out)        // [B]
{
    __shared__ __align__(16) f32x2 sT[2][1024];    // transpose dbuf  16 KB
    __shared__ __align__(8)  float2 sG2[3*NQ];     // (cy,sy) layers 1..3
    __shared__ float sA[NQ],sCa[NQ],sSa[NQ];
    __shared__ float sHz0[NQ],sHz1[NQ],sHz2[NQ],sWo[NQ];
    __shared__ float sRed[4];
    __shared__ float sBo;

    const int t   =threadIdx.x;
    const int lane=t&63;
    const int wv  =t>>6;
    const int wvs =__builtin_amdgcn_readfirstlane(wv);  // scalar wave id
    const int b   =blockIdx.x;

    // ---- issue GEMM loads first (latency overlaps the setup below) ----
    const float4* xp=reinterpret_cast<const float4*>(x)+(size_t)b*(IDIM/4);
    const float4 xv0=xp[lane],xv1=xp[64+lane],xv2=xp[128+lane];
    const int q0=wv, q1=wv+4;
    const int q2r=(wv<2)? wv+8 : wv;          // clamped row for waves 2,3 (discarded)
    const float4* p0=reinterpret_cast<const float4*>(Wr)+q0 *(IDIM/4);
    const float4* p1=reinterpret_cast<const float4*>(Wr)+q1 *(IDIM/4);
    const float4* p2=reinterpret_cast<const float4*>(Wr)+q2r*(IDIM/4);
    const float4 a0=p0[lane],a1=p0[64+lane],a2=p0[128+lane];
    const float4 b0=p1[lane],b1=p1[64+lane],b2=p1[128+lane];
    const float4 c0=p2[lane],c1=p2[64+lane],c2=p2[128+lane];

    // ---- setup (runs while loads are in flight) ----
    if(t<60){
        const int g=t>>1,l=g/NQ+1,w=g%NQ;
        const float h=0.5f*wts[(l*NQ+w)*2];
        reinterpret_cast<float*>(sG2)[t]=(t&1)? __sinf(h):__cosf(h);
    } else if(t<70)  sHz0[t-60]=0.5f*wts[(t-60)*2+1];
    else if(t<80)    sHz1[t-70]=0.5f*wts[((t-70)+NQ)*2+1];
    else if(t<90)    sHz2[t-80]=0.5f*wts[((t-80)+2*NQ)*2+1];
    else if(t<100)   sWo[t-90]=Wo[t-90];
    else if(t==100)  sBo=bo[0];

    // ---- three dots per wave, reduce chains interleaved ----
    float s0=xv0.x*a0.x+xv0.y*a0.y+xv0.z*a0.z+xv0.w*a0.w
            +xv1.x*a1.x+xv1.y*a1.y+xv1.z*a1.z+xv1.w*a1.w
            +xv2.x*a2.x+xv2.y*a2.y+xv2.z*a2.z+xv2.w*a2.w;
    float s1=xv0.x*b0.x+xv0.y*b0.y+xv0.z*b0.z+xv0.w*b0.w
            +xv1.x*b1.x+xv1.y*b1.y+xv1.z*b1.z+xv1.w*b1.w
            +xv2.x*b2.x+xv2.y*b2.y+xv2.z*b2.z+xv2.w*b2.w;
    float s2=xv0.x*c0.x+xv0.y*c0.y+xv0.z*c0.z+xv0.w*c0.w
            +xv1.x*c1.x+xv1.y*c1.y+xv1.z*c1.z+xv1.w*c1.w
            +xv2.x*c2.x+xv2.y*c2.y+xv2.z*c2.z+xv2.w*c2.w;
    s0+=lx<32>(s0); s1+=lx<32>(s1); s2+=lx<32>(s2);
    s0+=lx<16>(s0); s1+=lx<16>(s1); s2+=lx<16>(s2);
    s0+=lx<8>(s0);  s1+=lx<8>(s1);  s2+=lx<8>(s2);
    s0+=lx<4>(s0);  s1+=lx<4>(s1);  s2+=lx<4>(s2);
    s0+=lx<2>(s0);  s1+=lx<2>(s1);  s2+=lx<2>(s2);
    s0+=lx<1>(s0);  s1+=lx<1>(s1);  s2+=lx<1>(s2);
    if(lane==0){
        const float e0=__expf(2.f*(s0+br[q0]));
        sA[q0]=(1.f-__fdividef(2.f,e0+1.f))*1.57079632679489662f + wts[q0*2];
        const float e1=__expf(2.f*(s1+br[q1]));
        sA[q1]=(1.f-__fdividef(2.f,e1+1.f))*1.57079632679489662f + wts[q1*2];
        if(wv<2){
            const int q2=wv+8;
            const float e2=__expf(2.f*(s2+br[q2]));
            sA[q2]=(1.f-__fdividef(2.f,e2+1.f))*1.57079632679489662f + wts[q2*2];
        }
    }
    __syncthreads();

    if(t<NQ)           sCa[t]   =__cosf(0.5f*sA[t]);
    else if(t<2*NQ)    sSa[t-NQ]=__sinf(0.5f*sA[t-NQ]);
    __syncthreads();

    // ---- closed-form init @B0 (layer-0 RY merged + layer-0 RZ phases) ----
    float ac=1.f,ph=0.f;
    #pragma unroll
    for(int w=0;w<8;++w){                 // wires 0..7 <-> tid bits 7..0
        const int bit=(t>>(7-w))&1;
        ac*=bit? sSa[w]:sCa[w];
        ph+=bit? sHz0[w]:-sHz0[w];
    }
    f32x2 u[4];
    #pragma unroll
    for(int j=0;j<4;++j){                 // wires 8,9 <-> slot bits 1,0
        const float a =ac*((j&2)?sSa[8]:sCa[8])*((j&1)?sSa[9]:sCa[9]);
        const float pp_=ph+((j&2)?sHz0[8]:-sHz0[8])+((j&1)?sHz0[9]:-sHz0[9]);
        float s_,c_; __sincosf(pp_,&s_,&c_);
        u[j][0]=a*c_; u[j][1]=a*s_;
    }

    // ---- layers 1..3: RY gates + basis transposes + diagonal RZ passes ----
    int pp=0;
    ryp<1,2>(u,sG2,lane,wvs); ryp<1,3>(u,sG2,lane,wvs); ryp<1,4>(u,sG2,lane,wvs);
    ryp<1,5>(u,sG2,lane,wvs); ryp<1,6>(u,sG2,lane,wvs); ryp<1,7>(u,sG2,lane,wvs);
    ryp<1,8>(u,sG2,lane,wvs);
    transp<0>(u,sT[pp],t); pp^=1;
    ryp<1,0>(u,sG2,lane,wvs); ryp<1,1>(u,sG2,lane,wvs); ryp<1,9>(u,sG2,lane,wvs);
    diagp(u,DP1,sHz1,lane,wvs);

    ryp<2,0>(u,sG2,lane,wvs); ryp<2,2>(u,sG2,lane,wvs); ryp<2,4>(u,sG2,lane,wvs);
    ryp<2,6>(u,sG2,lane,wvs); ryp<2,7>(u,sG2,lane,wvs); ryp<2,8>(u,sG2,lane,wvs);
    ryp<2,9>(u,sG2,lane,wvs);
    transp<1>(u,sT[pp],t); pp^=1;
    ryp<2,1>(u,sG2,lane,wvs); ryp<2,3>(u,sG2,lane,wvs); ryp<2,5>(u,sG2,lane,wvs);
    diagp(u,DP2,sHz2,lane,wvs);

    ryp<3,5>(u,sG2,lane,wvs); ryp<3,6>(u,sG2,lane,wvs); ryp<3,7>(u,sG2,lane,wvs);
    ryp<3,9>(u,sG2,lane,wvs);
    transp<2>(u,sT[pp],t); pp^=1;
    ryp<3,0>(u,sG2,lane,wvs); ryp<3,1>(u,sG2,lane,wvs); ryp<3,2>(u,sG2,lane,wvs);
    ryp<3,8>(u,sG2,lane,wvs);
    transp<3>(u,sT[pp],t); pp^=1;
    ryp<3,3>(u,sG2,lane,wvs); ryp<3,4>(u,sG2,lane,wvs);
    // (layer-3 RZ is a pure phase before |.|^2 readout: dropped)

    // ---- readout @B3b: logit = sum_s p_s * g(s), Walsh butterfly for g ----
    float G[4]={0.f,0.f,0.f,0.f};
    #pragma unroll
    for(int w=0;w<NQ;++w){
        const int rtl=ZP.rt[w]&63, rtw=ZP.rt[w]>>6;
        const int pb=(__popc(lane&rtl) + __popc(wvs&rtw))&1;
        G[ZP.rl[w]] += pb? -sWo[w]:sWo[w];
    }
    const float g0=G[0]+G[1]+G[2]+G[3], g1=G[0]-G[1]+G[2]-G[3];
    const float g2=G[0]+G[1]-G[2]-G[3], g3=G[0]-G[1]-G[2]+G[3];
    float acc=(u[0][0]*u[0][0]+u[0][1]*u[0][1])*g0;
    acc=fmaf(u[1][0]*u[1][0]+u[1][1]*u[1][1],g1,acc);
    acc=fmaf(u[2][0]*u[2][0]+u[2][1]*u[2][1],g2,acc);
    acc=fmaf(u[3][0]*u[3][0]+u[3][1]*u[3][1],g3,acc);
    acc=red64(acc);
    if(lane==0) sRed[wv]=acc;
    __syncthreads();
    if(t==0){
        const float logit=sRed[0]+sRed[1]+sRed[2]+sRed[3]+sBo;
        out[b]=__fdividef(1.f,1.f+__expf(-logit));
    }
}

extern "C" void kernel_launch(void* const* d_in, const int* in_sizes, int n_in,
                              void* d_out, int out_size, void* d_ws, size_t ws_size,
                              hipStream_t stream) {
    const float* x  =(const float*)d_in[0];
    const float* Wr =(const float*)d_in[1];
    const float* br =(const float*)d_in[2];
    const float* wts=(const float*)d_in[3];
    const float* Wo =(const float*)d_in[4];
    const float* bo =(const float*)d_in[5];
    float* out=(float*)d_out;
    const int B=in_sizes[0]/IDIM;  // 1024

    qhead_kernel<<<B,BLK,0,stream>>>(x,Wr,br,wts,Wo,bo,out);
}